// Round 1
// baseline (1378.792 us; speedup 1.0000x reference)
//
#include <hip/hip_runtime.h>

#define B_   32
#define N_   8192
#define D_   8
#define P_   64
#define W_   128
#define T_   8
#define L2C_ 32
#define I2_  2320
#define K_   1024
#define OT_  128
#define NOT_ 19      // ceil(2320/128), last tile masked
#define KC_  64
#define NCH_ 16      // 1024 / 64

__device__ __forceinline__ int imin(int a, int b) { return a < b ? a : b; }

// ---------------------------------------------------------------------------
// k_main: per (p, o-tile) block.
//   H[32 x 128] = Xp[32 x 1024] @ W0[p]^T  (+ t·W1 + b1 + cap·W2), leaky 0.01
//   then partial z[32 x 128] += H @ W3[p,:,otile]^T  via atomicAdd (split-K over o)
// ---------------------------------------------------------------------------
__global__ __launch_bounds__(256, 3)
void k_main(const float* __restrict__ x, const float* __restrict__ t,
            const float* __restrict__ cap, const float* __restrict__ W0,
            const float* __restrict__ W1, const float* __restrict__ b1,
            const float* __restrict__ W2, const float* __restrict__ W3,
            const int* __restrict__ nodes_idx, float* __restrict__ z_pre)
{
    __shared__ __align__(16) float W0s[128 * 64];   // swizzled chunk [o:128][k:64]
    __shared__ __align__(16) float Xq[16 * 32 * 4]; // [k4:16][b:32][4]
    __shared__ float base_s[OT_];
    __shared__ float t_s[B_ * T_];

    const int tid = threadIdx.x;

    // bijective XCD swizzle: 1216 blocks = 8 XCDs x 152; co-locate each p's 19
    // tiles on one XCD so the x-partition (128KB) stays L2-resident.
    const int orig = blockIdx.x;
    const int wg   = (orig & 7) * (P_ * NOT_ / 8) + (orig >> 3);
    const int p    = wg / NOT_;
    const int o0   = (wg % NOT_) * OT_;

    // stage t (32x8 = 256 floats)
    t_s[tid] = t[tid];

    // base_s[o] = b1[p,o] + cap[p,:]·W2[p,o,:]   (b-independent)
    {
        const int o    = tid & 127;
        const int half = tid >> 7;
        const int og   = imin(o0 + o, I2_ - 1);
        const float* w2 = W2 + ((size_t)p * I2_ + og) * W_ + half * 64;
        const float* cp = cap + p * W_ + half * 64;
        float part = 0.f;
#pragma unroll
        for (int j = 0; j < 16; ++j) {
            float4 wv = *(const float4*)(w2 + j * 4);
            float4 cv = *(const float4*)(cp + j * 4);
            part += wv.x * cv.x + wv.y * cv.y + wv.z * cv.z + wv.w * cv.w;
        }
        if (half == 0) part += b1[(size_t)p * I2_ + og];
        W0s[tid] = part;                        // W0s as scratch (pre-staging)
        __syncthreads();
        if (tid < 128) base_s[tid] = W0s[tid] + W0s[tid + 128];
        // no barrier needed here: first loop barrier below orders the overwrite
    }

    // --- staging roles ---
    const int orow  = tid >> 1;     // 0..127 : o-row staged by this thread
    const int shalf = tid & 1;      // which 8-float4 half of the 64-float row
    const int og_st = imin(o0 + orow, I2_ - 1);
    const float* w0row = W0 + ((size_t)p * I2_ + og_st) * K_;
    const int sb   = tid & 31;      // b staged
    const int skk8 = tid >> 5;      // 0..7 : 8-k group staged

    // --- microkernel roles: 4b x 4o per thread ---
    const int ocol = tid & 31;      // o rows {ocol, ocol+32, ocol+64, ocol+96}
    const int brow = tid >> 5;      // 0..7
    const int b0   = brow * 4;

    float4 w0v[8], xa, xb;
    float acc[4][4];
#pragma unroll
    for (int i = 0; i < 4; ++i)
#pragma unroll
        for (int j = 0; j < 4; ++j) acc[i][j] = 0.f;

    auto load_chunk = [&](int kc16) {
        const int kc = kc16 * KC_;
#pragma unroll
        for (int j = 0; j < 8; ++j)
            w0v[j] = *(const float4*)(w0row + kc + (shalf * 8 + j) * 4);
        const int c    = kc16 * 8 + skk8;
        const int node = nodes_idx[p * W_ + c];
        const float* xr = x + ((size_t)sb * N_ + node) * D_;
        xa = *(const float4*)xr;
        xb = *(const float4*)(xr + 4);
    };

    auto write_chunk = [&]() {
#pragma unroll
        for (int j = 0; j < 8; ++j) {
            const int s  = shalf * 8 + j;
            const int sp = s ^ (orow & 7);          // XOR swizzle (low 3 bits)
            *(float4*)&W0s[orow * 64 + sp * 4] = w0v[j];
        }
        *(float4*)&Xq[((skk8 * 2 + 0) * 32 + sb) * 4] = xa;
        *(float4*)&Xq[((skk8 * 2 + 1) * 32 + sb) * 4] = xb;
    };

    load_chunk(0);
    for (int kc16 = 0; kc16 < NCH_; ++kc16) {
        __syncthreads();             // previous chunk's compute done
        write_chunk();
        if (kc16 + 1 < NCH_) load_chunk(kc16 + 1);   // prefetch under compute
        __syncthreads();             // staged data visible

        const int swz = ocol & 7;
#pragma unroll 4
        for (int kk4 = 0; kk4 < 16; ++kk4) {
            float4 Wv[4], Xv[4];
#pragma unroll
            for (int oi = 0; oi < 4; ++oi)
                Wv[oi] = *(const float4*)&W0s[(ocol + 32 * oi) * 64 + ((kk4 ^ swz) * 4)];
#pragma unroll
            for (int bi = 0; bi < 4; ++bi)
                Xv[bi] = *(const float4*)&Xq[(kk4 * 32 + b0 + bi) * 4];
#pragma unroll
            for (int oi = 0; oi < 4; ++oi)
#pragma unroll
                for (int bi = 0; bi < 4; ++bi) {
                    acc[bi][oi] += Xv[bi].x * Wv[oi].x;
                    acc[bi][oi] += Xv[bi].y * Wv[oi].y;
                    acc[bi][oi] += Xv[bi].z * Wv[oi].z;
                    acc[bi][oi] += Xv[bi].w * Wv[oi].w;
                }
        }
    }

    // --- epilogue: + t·W1 + base, leaky_relu(0.01), mask tail ---
    float hval[4][4];
#pragma unroll
    for (int oi = 0; oi < 4; ++oi) {
        const int row = ocol + 32 * oi;
        const int og  = o0 + row;
        const int ogc = imin(og, I2_ - 1);
        const float4 w1a = *(const float4*)(W1 + ((size_t)p * I2_ + ogc) * T_);
        const float4 w1b = *(const float4*)(W1 + ((size_t)p * I2_ + ogc) * T_ + 4);
        const float bs = base_s[row];
#pragma unroll
        for (int bi = 0; bi < 4; ++bi) {
            const float* tb = &t_s[(b0 + bi) * T_];
            float s = acc[bi][oi] + bs
                    + tb[0] * w1a.x + tb[1] * w1a.y + tb[2] * w1a.z + tb[3] * w1a.w
                    + tb[4] * w1b.x + tb[5] * w1b.y + tb[6] * w1b.z + tb[7] * w1b.w;
            s = (s > 0.f) ? s : 0.01f * s;
            hval[bi][oi] = (og < I2_) ? s : 0.f;
        }
    }

    __syncthreads();                 // all waves done reading W0s
    float* hs = W0s;                 // reuse as h[b:32][132] (pad 4 vs bank wrap)
#pragma unroll
    for (int oi = 0; oi < 4; ++oi)
#pragma unroll
        for (int bi = 0; bi < 4; ++bi)
            hs[(b0 + bi) * 132 + (ocol + 32 * oi)] = hval[bi][oi];
    __syncthreads();

    // --- partial z: z[b,w] += sum_{o in tile} h[b,o] * W3[p,w,o] ---
    const int zb  = tid & 31;        // b
    const int wg8 = tid >> 5;        // w group: w = wg8*16 + j
    float accz[16];
#pragma unroll
    for (int j = 0; j < 16; ++j) accz[j] = 0.f;

    for (int o4 = 0; o4 < 32; ++o4) {
        const int og4 = o0 + o4 * 4;
        if (og4 >= I2_) break;       // uniform; tail h already zero
        const float4 hv = *(const float4*)&hs[zb * 132 + o4 * 4];
#pragma unroll
        for (int j = 0; j < 16; ++j) {
            const int w = wg8 * 16 + j;
            const float4 wv = *(const float4*)(W3 + ((size_t)(p * W_ + w)) * I2_ + og4);
            accz[j] += hv.x * wv.x + hv.y * wv.y + hv.z * wv.z + hv.w * wv.w;
        }
    }
    float* zp = z_pre + ((size_t)zb * P_ + p) * W_ + wg8 * 16;
#pragma unroll
    for (int j = 0; j < 16; ++j) atomicAdd(zp + j, accz[j]);
}

// ---------------------------------------------------------------------------
// k_zwx: z = relu(z_pre + b3); wx[b,p,d] = sum_c z[b,p,c] * x[b, gather(p,c), d]
// (partition_index is the identity -> scatter+contract collapses to this)
// ---------------------------------------------------------------------------
__global__ __launch_bounds__(128)
void k_zwx(const float* __restrict__ x, const float* __restrict__ b3,
           const int* __restrict__ nodes_idx, const float* __restrict__ z_pre,
           float* __restrict__ wx)
{
    __shared__ float red[128 * 8];
    const int b = blockIdx.x >> 6;
    const int p = blockIdx.x & 63;
    const int c = threadIdx.x;

    float zv = z_pre[((size_t)b * P_ + p) * W_ + c] + b3[p * W_ + c];
    zv = zv > 0.f ? zv : 0.f;

    const int node = nodes_idx[p * W_ + c];
    const float* xr = x + ((size_t)b * N_ + node) * D_;
    const float4 x1 = *(const float4*)xr;
    const float4 x2 = *(const float4*)(xr + 4);
    red[c * 8 + 0] = zv * x1.x; red[c * 8 + 1] = zv * x1.y;
    red[c * 8 + 2] = zv * x1.z; red[c * 8 + 3] = zv * x1.w;
    red[c * 8 + 4] = zv * x2.x; red[c * 8 + 5] = zv * x2.y;
    red[c * 8 + 6] = zv * x2.z; red[c * 8 + 7] = zv * x2.w;
    __syncthreads();
    for (int s = 64; s > 0; s >>= 1) {
        if (c < s) {
#pragma unroll
            for (int d = 0; d < 8; ++d) red[c * 8 + d] += red[(c + s) * 8 + d];
        }
        __syncthreads();
    }
    if (c < 8) wx[((size_t)b * P_ + p) * D_ + c] = red[c];
}

// ---------------------------------------------------------------------------
// k_conv: y[b,l] = leaky( sum_{p,d} wx[b,p,d]*conv_w[l,d,p] + conv_b[l], 0.02 )
// ---------------------------------------------------------------------------
__global__ __launch_bounds__(256)
void k_conv(const float* __restrict__ wx, const float* __restrict__ conv_w,
            const float* __restrict__ conv_b, float* __restrict__ out)
{
    __shared__ float red[256];
    const int b  = blockIdx.x;
    const int l  = threadIdx.x & 31;
    const int pg = threadIdx.x >> 5;
    float acc = 0.f;
    for (int pp = pg * 8; pp < pg * 8 + 8; ++pp) {
#pragma unroll
        for (int d = 0; d < 8; ++d)
            acc += wx[((size_t)b * P_ + pp) * D_ + d] * conv_w[(l * D_ + d) * P_ + pp];
    }
    red[threadIdx.x] = acc;
    __syncthreads();
    if (threadIdx.x < 32) {
        float v = conv_b[l];
#pragma unroll
        for (int g = 0; g < 8; ++g) v += red[g * 32 + l];
        out[b * L2C_ + l] = v > 0.f ? v : 0.02f * v;
    }
}

// ---------------------------------------------------------------------------
extern "C" void kernel_launch(void* const* d_in, const int* in_sizes, int n_in,
                              void* d_out, int out_size, void* d_ws, size_t ws_size,
                              hipStream_t stream)
{
    const float* x   = (const float*)d_in[0];
    const float* t   = (const float*)d_in[1];
    const float* cap = (const float*)d_in[2];
    // d_in[3] = partition_index (identity selection matrix; realized directly)
    const float* W0  = (const float*)d_in[4];
    const float* W1  = (const float*)d_in[5];
    const float* b1  = (const float*)d_in[6];
    const float* W2  = (const float*)d_in[7];
    const float* W3  = (const float*)d_in[8];
    const float* b3  = (const float*)d_in[9];
    const float* cw  = (const float*)d_in[10];
    const float* cb  = (const float*)d_in[11];
    const int*  nidx = (const int*)d_in[12];

    float* z_pre = (float*)d_ws;                 // [32][64][128] = 1 MB
    float* wx    = z_pre + (size_t)B_ * P_ * W_; // [32][64][8]   = 64 KB

    hipMemsetAsync(z_pre, 0, (size_t)B_ * P_ * W_ * sizeof(float), stream);
    k_main<<<P_ * NOT_, 256, 0, stream>>>(x, t, cap, W0, W1, b1, W2, W3, nidx, z_pre);
    k_zwx<<<B_ * P_, 128, 0, stream>>>(x, b3, nidx, z_pre, wx);
    k_conv<<<B_, 256, 0, stream>>>(wx, cw, cb, (float*)d_out);
}

// Round 2
// 1309.409 us; speedup vs baseline: 1.0530x; 1.0530x over previous
//
#include <hip/hip_runtime.h>

#define B_   32
#define N_   8192
#define D_   8
#define P_   64
#define W_   128
#define T_   8
#define L2C_ 32
#define I2_  2320
#define K_   1024
#define OT_  128
#define NOT_ 19      // ceil(2320/128), last tile masked
#define KC_  64
#define NCH_ 16      // 1024 / 64

__device__ __forceinline__ int imin(int a, int b) { return a < b ? a : b; }

// ---------------------------------------------------------------------------
// k_main: per (p, o-tile) block.
//   H[32 x 128] = Xp[32 x 1024] @ W0[p]^T  (+ t·W1 + b1 + cap·W2), leaky 0.01
//   then partial z[32 x 128] = H @ W3[p,:,otile]^T
//   USE_ATOMIC=0: store partial to z_part[p][ot][b][w] (coalesced, no atomics)
//   USE_ATOMIC=1: atomicAdd into z[p][b][w]  (fallback if ws too small)
// ---------------------------------------------------------------------------
template <int USE_ATOMIC>
__global__ __launch_bounds__(256, 3)
void k_main(const float* __restrict__ x, const float* __restrict__ t,
            const float* __restrict__ cap, const float* __restrict__ W0,
            const float* __restrict__ W1, const float* __restrict__ b1,
            const float* __restrict__ W2, const float* __restrict__ W3,
            const int* __restrict__ nodes_idx, float* __restrict__ zdst)
{
    __shared__ __align__(16) float W0s[128 * 64];   // swizzled chunk [o:128][k:64]
    __shared__ __align__(16) float Xq[16 * 32 * 4]; // [k4:16][b:32][4]
    __shared__ float base_s[OT_];
    __shared__ float t_s[B_ * T_];

    const int tid = threadIdx.x;

    // bijective XCD swizzle: 1216 blocks = 8 XCDs x 152; co-locate each p's 19
    // tiles on one XCD so the x-partition (128KB) stays L2-resident.
    const int orig = blockIdx.x;
    const int wg   = (orig & 7) * (P_ * NOT_ / 8) + (orig >> 3);
    const int p    = wg / NOT_;
    const int oti  = wg % NOT_;
    const int o0   = oti * OT_;

    // stage t (32x8 = 256 floats)
    t_s[tid] = t[tid];

    // base_s[o] = b1[p,o] + cap[p,:]·W2[p,o,:]   (b-independent)
    {
        const int o    = tid & 127;
        const int half = tid >> 7;
        const int og   = imin(o0 + o, I2_ - 1);
        const float* w2 = W2 + ((size_t)p * I2_ + og) * W_ + half * 64;
        const float* cp = cap + p * W_ + half * 64;
        float part = 0.f;
#pragma unroll
        for (int j = 0; j < 16; ++j) {
            float4 wv = *(const float4*)(w2 + j * 4);
            float4 cv = *(const float4*)(cp + j * 4);
            part += wv.x * cv.x + wv.y * cv.y + wv.z * cv.z + wv.w * cv.w;
        }
        if (half == 0) part += b1[(size_t)p * I2_ + og];
        W0s[tid] = part;                        // W0s as scratch (pre-staging)
        __syncthreads();
        if (tid < 128) base_s[tid] = W0s[tid] + W0s[tid + 128];
        // no barrier needed here: first loop barrier below orders the overwrite
    }

    // --- staging roles ---
    const int orow  = tid >> 1;     // 0..127 : o-row staged by this thread
    const int shalf = tid & 1;      // which 8-float4 half of the 64-float row
    const int og_st = imin(o0 + orow, I2_ - 1);
    const float* w0row = W0 + ((size_t)p * I2_ + og_st) * K_;
    const int sb   = tid & 31;      // b staged
    const int skk8 = tid >> 5;      // 0..7 : 8-k group staged

    // --- microkernel roles: 4b x 4o per thread ---
    const int ocol = tid & 31;      // o rows {ocol, ocol+32, ocol+64, ocol+96}
    const int brow = tid >> 5;      // 0..7
    const int b0   = brow * 4;

    float4 w0v[8], xa, xb;
    float acc[4][4];
#pragma unroll
    for (int i = 0; i < 4; ++i)
#pragma unroll
        for (int j = 0; j < 4; ++j) acc[i][j] = 0.f;

    auto load_chunk = [&](int kc16) {
        const int kc = kc16 * KC_;
#pragma unroll
        for (int j = 0; j < 8; ++j)
            w0v[j] = *(const float4*)(w0row + kc + (shalf * 8 + j) * 4);
        const int c    = kc16 * 8 + skk8;
        const int node = nodes_idx[p * W_ + c];
        const float* xr = x + ((size_t)sb * N_ + node) * D_;
        xa = *(const float4*)xr;
        xb = *(const float4*)(xr + 4);
    };

    auto write_chunk = [&]() {
#pragma unroll
        for (int j = 0; j < 8; ++j) {
            const int s  = shalf * 8 + j;
            const int sp = s ^ (orow & 7);          // XOR swizzle (low 3 bits)
            *(float4*)&W0s[orow * 64 + sp * 4] = w0v[j];
        }
        *(float4*)&Xq[((skk8 * 2 + 0) * 32 + sb) * 4] = xa;
        *(float4*)&Xq[((skk8 * 2 + 1) * 32 + sb) * 4] = xb;
    };

    load_chunk(0);
    for (int kc16 = 0; kc16 < NCH_; ++kc16) {
        __syncthreads();             // previous chunk's compute done
        write_chunk();
        if (kc16 + 1 < NCH_) load_chunk(kc16 + 1);   // prefetch under compute
        __syncthreads();             // staged data visible

        const int swz = ocol & 7;
#pragma unroll 4
        for (int kk4 = 0; kk4 < 16; ++kk4) {
            float4 Wv[4], Xv[4];
#pragma unroll
            for (int oi = 0; oi < 4; ++oi)
                Wv[oi] = *(const float4*)&W0s[(ocol + 32 * oi) * 64 + ((kk4 ^ swz) * 4)];
#pragma unroll
            for (int bi = 0; bi < 4; ++bi)
                Xv[bi] = *(const float4*)&Xq[(kk4 * 32 + b0 + bi) * 4];
#pragma unroll
            for (int oi = 0; oi < 4; ++oi)
#pragma unroll
                for (int bi = 0; bi < 4; ++bi) {
                    acc[bi][oi] += Xv[bi].x * Wv[oi].x;
                    acc[bi][oi] += Xv[bi].y * Wv[oi].y;
                    acc[bi][oi] += Xv[bi].z * Wv[oi].z;
                    acc[bi][oi] += Xv[bi].w * Wv[oi].w;
                }
        }
    }

    // --- epilogue: + t·W1 + base, leaky_relu(0.01), mask tail ---
    float hval[4][4];
#pragma unroll
    for (int oi = 0; oi < 4; ++oi) {
        const int row = ocol + 32 * oi;
        const int og  = o0 + row;
        const int ogc = imin(og, I2_ - 1);
        const float4 w1a = *(const float4*)(W1 + ((size_t)p * I2_ + ogc) * T_);
        const float4 w1b = *(const float4*)(W1 + ((size_t)p * I2_ + ogc) * T_ + 4);
        const float bs = base_s[row];
#pragma unroll
        for (int bi = 0; bi < 4; ++bi) {
            const float* tb = &t_s[(b0 + bi) * T_];
            float s = acc[bi][oi] + bs
                    + tb[0] * w1a.x + tb[1] * w1a.y + tb[2] * w1a.z + tb[3] * w1a.w
                    + tb[4] * w1b.x + tb[5] * w1b.y + tb[6] * w1b.z + tb[7] * w1b.w;
            s = (s > 0.f) ? s : 0.01f * s;
            hval[bi][oi] = (og < I2_) ? s : 0.f;
        }
    }

    __syncthreads();                 // all waves done reading W0s
    float* hs = W0s;                 // reuse as h[b:32][132] (pad vs bank wrap)
#pragma unroll
    for (int oi = 0; oi < 4; ++oi)
#pragma unroll
        for (int bi = 0; bi < 4; ++bi)
            hs[(b0 + bi) * 132 + (ocol + 32 * oi)] = hval[bi][oi];
    __syncthreads();

    // --- partial z: z[b,w] = sum_{o in tile} h[b,o] * W3[p,w,o] ---
    const int zb  = tid & 31;        // b
    const int wg8 = tid >> 5;        // w group: w = wg8*16 + j
    float accz[16];
#pragma unroll
    for (int j = 0; j < 16; ++j) accz[j] = 0.f;

    for (int o4 = 0; o4 < 32; ++o4) {
        const int og4 = o0 + o4 * 4;
        if (og4 >= I2_) break;       // uniform; tail h already zero
        const float4 hv = *(const float4*)&hs[zb * 132 + o4 * 4];
#pragma unroll
        for (int j = 0; j < 16; ++j) {
            const int w = wg8 * 16 + j;
            const float4 wv = *(const float4*)(W3 + ((size_t)(p * W_ + w)) * I2_ + og4);
            accz[j] += hv.x * wv.x + hv.y * wv.y + hv.z * wv.z + hv.w * wv.w;
        }
    }

    if (USE_ATOMIC) {
        // fallback: z[p][b][w] via device atomics (only if ws too small)
        float* zp = zdst + ((size_t)p * B_ + zb) * W_ + wg8 * 16;
#pragma unroll
        for (int j = 0; j < 16; ++j) atomicAdd(zp + j, accz[j]);
    } else {
        // transpose through LDS so the global store is fully coalesced.
        __syncthreads();             // all waves done reading hs
        float* zs = W0s;             // [b][w ^ ((b&31)<<2)] : 4096 floats
#pragma unroll
        for (int j = 0; j < 16; ++j) {
            const int w = wg8 * 16 + j;
            zs[zb * W_ + (w ^ ((zb & 31) << 2))] = accz[j];
        }
        __syncthreads();
        float* zo = zdst + (size_t)(p * NOT_ + oti) * (B_ * W_);
#pragma unroll
        for (int r = 0; r < 16; ++r) {
            const int i = r * 256 + tid;
            const int b = i >> 7, w = i & 127;
            zo[i] = zs[b * W_ + (w ^ ((b & 31) << 2))];
        }
    }
}

// ---------------------------------------------------------------------------
// k_zwx: z = relu(sum_ot z_part + b3); wx[b,p,d] = sum_c z[b,p,c]*x[b,gather,d]
// (partition_index is the identity -> scatter+contract collapses to this)
// ---------------------------------------------------------------------------
__global__ __launch_bounds__(128)
void k_zwx(const float* __restrict__ x, const float* __restrict__ b3,
           const int* __restrict__ nodes_idx, const float* __restrict__ z_part,
           int nparts, float* __restrict__ wx)
{
    __shared__ float red[128 * 8];
    const int b = blockIdx.x >> 6;
    const int p = blockIdx.x & 63;
    const int c = threadIdx.x;

    float zv = b3[p * W_ + c];
    for (int ot = 0; ot < nparts; ++ot)
        zv += z_part[((size_t)(p * nparts + ot) * B_ + b) * W_ + c];
    zv = zv > 0.f ? zv : 0.f;

    const int node = nodes_idx[p * W_ + c];
    const float* xr = x + ((size_t)b * N_ + node) * D_;
    const float4 x1 = *(const float4*)xr;
    const float4 x2 = *(const float4*)(xr + 4);
    red[c * 8 + 0] = zv * x1.x; red[c * 8 + 1] = zv * x1.y;
    red[c * 8 + 2] = zv * x1.z; red[c * 8 + 3] = zv * x1.w;
    red[c * 8 + 4] = zv * x2.x; red[c * 8 + 5] = zv * x2.y;
    red[c * 8 + 6] = zv * x2.z; red[c * 8 + 7] = zv * x2.w;
    __syncthreads();
    for (int s = 64; s > 0; s >>= 1) {
        if (c < s) {
#pragma unroll
            for (int d = 0; d < 8; ++d) red[c * 8 + d] += red[(c + s) * 8 + d];
        }
        __syncthreads();
    }
    if (c < 8) wx[((size_t)b * P_ + p) * D_ + c] = red[c];
}

// ---------------------------------------------------------------------------
// k_conv: y[b,l] = leaky( sum_{p,d} wx[b,p,d]*conv_w[l,d,p] + conv_b[l], 0.02 )
// ---------------------------------------------------------------------------
__global__ __launch_bounds__(256)
void k_conv(const float* __restrict__ wx, const float* __restrict__ conv_w,
            const float* __restrict__ conv_b, float* __restrict__ out)
{
    __shared__ float red[256];
    const int b  = blockIdx.x;
    const int l  = threadIdx.x & 31;
    const int pg = threadIdx.x >> 5;
    float acc = 0.f;
    for (int pp = pg * 8; pp < pg * 8 + 8; ++pp) {
#pragma unroll
        for (int d = 0; d < 8; ++d)
            acc += wx[((size_t)b * P_ + pp) * D_ + d] * conv_w[(l * D_ + d) * P_ + pp];
    }
    red[threadIdx.x] = acc;
    __syncthreads();
    if (threadIdx.x < 32) {
        float v = conv_b[l];
#pragma unroll
        for (int g = 0; g < 8; ++g) v += red[g * 32 + l];
        out[b * L2C_ + l] = v > 0.f ? v : 0.02f * v;
    }
}

// ---------------------------------------------------------------------------
extern "C" void kernel_launch(void* const* d_in, const int* in_sizes, int n_in,
                              void* d_out, int out_size, void* d_ws, size_t ws_size,
                              hipStream_t stream)
{
    const float* x   = (const float*)d_in[0];
    const float* t   = (const float*)d_in[1];
    const float* cap = (const float*)d_in[2];
    // d_in[3] = partition_index (identity selection matrix; realized directly)
    const float* W0  = (const float*)d_in[4];
    const float* W1  = (const float*)d_in[5];
    const float* b1  = (const float*)d_in[6];
    const float* W2  = (const float*)d_in[7];
    const float* W3  = (const float*)d_in[8];
    const float* b3  = (const float*)d_in[9];
    const float* cw  = (const float*)d_in[10];
    const float* cb  = (const float*)d_in[11];
    const int*  nidx = (const int*)d_in[12];

    const size_t zpart_elems = (size_t)P_ * NOT_ * B_ * W_;   // 19.9 MB
    const size_t zatom_elems = (size_t)P_ * B_ * W_;          // 1 MB
    const size_t wx_elems    = (size_t)B_ * P_ * D_;
    const bool   use_part    = ws_size >= (zpart_elems + wx_elems) * sizeof(float);

    float* zbuf = (float*)d_ws;
    float* wx   = zbuf + (use_part ? zpart_elems : zatom_elems);

    if (use_part) {
        k_main<0><<<P_ * NOT_, 256, 0, stream>>>(x, t, cap, W0, W1, b1, W2, W3,
                                                 nidx, zbuf);
        k_zwx<<<B_ * P_, 128, 0, stream>>>(x, b3, nidx, zbuf, NOT_, wx);
    } else {
        hipMemsetAsync(zbuf, 0, zatom_elems * sizeof(float), stream);
        k_main<1><<<P_ * NOT_, 256, 0, stream>>>(x, t, cap, W0, W1, b1, W2, W3,
                                                 nidx, zbuf);
        k_zwx<<<B_ * P_, 128, 0, stream>>>(x, b3, nidx, zbuf, 1, wx);
    }
    k_conv<<<B_, 256, 0, stream>>>(wx, cw, cb, (float*)d_out);
}